// Round 4
// baseline (127.851 us; speedup 1.0000x reference)
//
#include <hip/hip_runtime.h>

#define BLK 128
#define NJ 8

// Fully fused, all-f32 (reference dtypes: float32 in, float32 out — round-3
// post-mortem: R1/R3 byte-identical results proved the readback is f32 and
// the only bug was treating f32 inputs as bf16).
// One block per row i:
//  Phase 1: stage s -> LDS, compact active-neighbor list (dist<0.5), conv1 ->
//           conv2 (thread t owns conv2 channel t, 64 weights in VGPRs) ->
//           masked max-pool row i.
//  Phase 2: 4-layer MLP head + gain epilogue, float2 store.
__global__ __launch_bounds__(BLK) void NetworkAction_86131274154571_kernel(
    const float* __restrict__ s,    const float* __restrict__ g,
    const float* __restrict__ w1g,  const float* __restrict__ b1g,
    const float* __restrict__ w2g,  const float* __restrict__ b2g,
    const float* __restrict__ fc1w, const float* __restrict__ fc1b,
    const float* __restrict__ fc2w, const float* __restrict__ fc2b,
    const float* __restrict__ fc3w, const float* __restrict__ fc3b,
    const float* __restrict__ fc4w, const float* __restrict__ fc4b,
    float2* __restrict__ out)
{
    __shared__ float4 slds[1024];        // staged s rows
    __shared__ float w1[320];            // conv1_w 64x5
    __shared__ float b1[64];
    __shared__ float h1buf[NJ][64];
    __shared__ int act[1024];
    __shared__ int cnt;
    __shared__ float feat[132];
    __shared__ float z1[64];
    __shared__ float z2[128];
    __shared__ float z3[64];
    __shared__ float kk[4];

    const int tid = threadIdx.x;
    const int i = blockIdx.x;

    if (tid == 0) cnt = 0;

    // stage s (1024x4 f32, 16B rows) -> LDS as float4
    for (int j = tid; j < 1024; j += BLK)
        slds[j] = ((const float4*)s)[j];
    for (int q = tid; q < 320; q += BLK) w1[q] = w1g[q];
    if (tid < 64) b1[tid] = b1g[tid];

    // conv2 row o=tid -> 64 f32 in registers (256B row, float4-aligned)
    float w2r[64];
    {
        const float4* wrow = (const float4*)(w2g + tid * 64);
        #pragma unroll
        for (int q = 0; q < 16; ++q) {
            float4 u = wrow[q];
            w2r[4*q+0] = u.x; w2r[4*q+1] = u.y;
            w2r[4*q+2] = u.z; w2r[4*q+3] = u.w;
        }
    }
    const float b2r = b2g[tid];

    __syncthreads();

    const float4 si = slds[i];

    // mask + compact active-j list (order irrelevant: max-pool commutative)
    for (int j = tid; j < 1024; j += BLK) {
        float dx = si.x - slds[j].x;
        float dy = si.y - slds[j].y;
        float d2 = dx * dx + dy * dy;
        if (d2 < 0.25f) {
            int p = atomicAdd(&cnt, 1);
            act[p] = j;
        }
    }
    __syncthreads();
    const int n_act = cnt;   // >= 1 (diagonal always active)

    float m = 0.0f;          // relu of conv2 folded into max with 0
    for (int base = 0; base < n_act; base += NJ) {
        const int nj = min(NJ, n_act - base);
        // conv1 for up to NJ neighbors: 64*nj items over 128 threads
        for (int w = tid; w < (nj << 6); w += BLK) {
            const int c = w & 63, slot = w >> 6;
            const int j = act[base + slot];
            const float4 sj = slds[j];
            const float x0 = si.x - sj.x, x1 = si.y - sj.y;
            const float x2 = si.z - sj.z, x3 = si.w - sj.w;
            const float x4 = (j == i) ? 1.0f : 0.0f;
            const float* wr = &w1[c * 5];
            float h = b1[c];
            h = fmaf(wr[0], x0, h);
            h = fmaf(wr[1], x1, h);
            h = fmaf(wr[2], x2, h);
            h = fmaf(wr[3], x3, h);
            h = fmaf(wr[4], x4, h);
            h1buf[slot][c] = fmaxf(h, 0.0f);
        }
        __syncthreads();
        // conv2: 64 reg-weight FMAs per neighbor, broadcast ds_read_b128 of h1
        for (int slot = 0; slot < nj; ++slot) {
            float acc = b2r;
            const float4* hv = (const float4*)(&h1buf[slot][0]);
            #pragma unroll
            for (int q = 0; q < 16; ++q) {
                float4 h4 = hv[q];
                acc = fmaf(w2r[4*q+0], h4.x, acc);
                acc = fmaf(w2r[4*q+1], h4.y, acc);
                acc = fmaf(w2r[4*q+2], h4.z, acc);
                acc = fmaf(w2r[4*q+3], h4.w, acc);
            }
            m = fmaxf(m, acc);
        }
        __syncthreads();
    }

    // ---- MLP head for row i, fused in-block ----
    feat[tid] = m;                       // pooled[0..127]
    if (tid == 0) {
        float2 gi = ((const float2*)g)[i];
        feat[128] = si.x - gi.x;
        feat[129] = si.y - gi.y;
        feat[130] = si.z;
        feat[131] = si.w;
    }
    __syncthreads();

    // fc1: 132 -> 64 (threads 0..63); row = 528B, float4-aligned
    if (tid < 64) {
        float acc = fc1b[tid];
        const float4* wv = (const float4*)(fc1w + tid * 132);
        #pragma unroll
        for (int q = 0; q < 33; ++q) {
            float4 u = wv[q];
            int k = q * 4;
            acc = fmaf(u.x, feat[k+0], acc);
            acc = fmaf(u.y, feat[k+1], acc);
            acc = fmaf(u.z, feat[k+2], acc);
            acc = fmaf(u.w, feat[k+3], acc);
        }
        z1[tid] = fmaxf(acc, 0.0f);
    }
    __syncthreads();

    // fc2: 64 -> 128 (all 128 threads); row = 256B
    {
        float acc = fc2b[tid];
        const float4* wv = (const float4*)(fc2w + tid * 64);
        #pragma unroll
        for (int q = 0; q < 16; ++q) {
            float4 u = wv[q];
            int k = q * 4;
            acc = fmaf(u.x, z1[k+0], acc);
            acc = fmaf(u.y, z1[k+1], acc);
            acc = fmaf(u.z, z1[k+2], acc);
            acc = fmaf(u.w, z1[k+3], acc);
        }
        z2[tid] = fmaxf(acc, 0.0f);
    }
    __syncthreads();

    // fc3: 128 -> 64 (threads 0..63); row = 512B
    if (tid < 64) {
        float acc = fc3b[tid];
        const float4* wv = (const float4*)(fc3w + tid * 128);
        #pragma unroll
        for (int q = 0; q < 32; ++q) {
            float4 u = wv[q];
            int k = q * 4;
            acc = fmaf(u.x, z2[k+0], acc);
            acc = fmaf(u.y, z2[k+1], acc);
            acc = fmaf(u.z, z2[k+2], acc);
            acc = fmaf(u.w, z2[k+3], acc);
        }
        z3[tid] = fmaxf(acc, 0.0f);
    }
    __syncthreads();

    // fc4 (64->4) + sigmoid gain
    if (tid < 4) {
        float acc = fc4b[tid];
        const float4* wv = (const float4*)(fc4w + tid * 64);
        #pragma unroll
        for (int q = 0; q < 16; ++q) {
            float4 u = wv[q];
            int k = q * 4;
            acc = fmaf(u.x, z3[k+0], acc);
            acc = fmaf(u.y, z3[k+1], acc);
            acc = fmaf(u.z, z3[k+2], acc);
            acc = fmaf(u.w, z3[k+3], acc);
        }
        kk[tid] = 2.0f / (1.0f + expf(-acc)) - 1.0f;   // 2*sigmoid - 1
    }
    __syncthreads();

    if (tid == 0) {
        float sgx = feat[128], sgy = feat[129];
        float vx  = feat[130], vy  = feat[131];
        float ax = -(kk[0] * sgx + kk[1] * vx);
        float ay = -(kk[2] * sgy + kk[3] * vy);
        out[i] = make_float2(ax, ay);
    }
}

extern "C" void kernel_launch(void* const* d_in, const int* in_sizes, int n_in,
                              void* d_out, int out_size, void* d_ws, size_t ws_size,
                              hipStream_t stream) {
    const float* s    = (const float*)d_in[0];
    const float* g    = (const float*)d_in[1];
    const float* c1w  = (const float*)d_in[2];
    const float* c1b  = (const float*)d_in[3];
    const float* c2w  = (const float*)d_in[4];
    const float* c2b  = (const float*)d_in[5];
    const float* fc1w = (const float*)d_in[6];
    const float* fc1b = (const float*)d_in[7];
    const float* fc2w = (const float*)d_in[8];
    const float* fc2b = (const float*)d_in[9];
    const float* fc3w = (const float*)d_in[10];
    const float* fc3b = (const float*)d_in[11];
    const float* fc4w = (const float*)d_in[12];
    const float* fc4b = (const float*)d_in[13];

    float2* out = (float2*)d_out;   // 1024 x (ax, ay) f32

    NetworkAction_86131274154571_kernel<<<1024, BLK, 0, stream>>>(
        s, g, c1w, c1b, c2w, c2b, fc1w, fc1b, fc2w, fc2b,
        fc3w, fc3b, fc4w, fc4b, out);
}